// Round 6
// baseline (213.804 us; speedup 1.0000x reference)
//
#include <hip/hip_runtime.h>
#include <hip/hip_bf16.h>
#include <stdint.h>

#define BATCH 8192
#define IN    1024
#define OUTD  1024
#define PBASIS 8

typedef __attribute__((ext_vector_type(8))) short bf16x8;
typedef __attribute__((ext_vector_type(4))) float floatx4;

__device__ __forceinline__ unsigned short f2bf(float f) {
    union { float f; unsigned u; } v; v.f = f;
    unsigned u = v.u;
    u += 0x7fffu + ((u >> 16) & 1u);   // RNE; inputs finite randn
    return (unsigned short)(u >> 16);
}

// Fused prep: blocks [0,4096) convert x -> bf16 (8 elem/thread);
// blocks [4096,6144) compute w_eff = bf16(sum_p coef * w) (2 elem/thread).
__global__ void prep_kernel(const float* __restrict__ x,
                            const float* __restrict__ coef,
                            const float* __restrict__ w,
                            unsigned short* __restrict__ xb,
                            unsigned short* __restrict__ weff) {
    int b = blockIdx.x;
    int tid = threadIdx.x;
    if (b < 4096) {
        int idx = b * 256 + tid;
        const float4* p = (const float4*)(x + (size_t)idx * 8);
        float4 a = p[0], c = p[1];
        uint4 o;
        o.x = (unsigned)f2bf(a.x) | ((unsigned)f2bf(a.y) << 16);
        o.y = (unsigned)f2bf(a.z) | ((unsigned)f2bf(a.w) << 16);
        o.z = (unsigned)f2bf(c.x) | ((unsigned)f2bf(c.y) << 16);
        o.w = (unsigned)f2bf(c.z) | ((unsigned)f2bf(c.w) << 16);
        ((uint4*)xb)[idx] = o;
    } else {
        int idx = (b - 4096) * 256 + tid;   // element pair index
        size_t e0 = (size_t)idx * 2;
        const float4* c4 = (const float4*)(coef + e0 * PBASIS);
        float4 a = c4[0], bb = c4[1], c = c4[2], d = c4[3];
        float s0 = (a.x + a.y + a.z + a.w) + (bb.x + bb.y + bb.z + bb.w);
        float s1 = (c.x + c.y + c.z + c.w) + (d.x + d.y + d.z + d.w);
        float2 ww = ((const float2*)w)[idx];
        unsigned b0 = f2bf(s0 * ww.x);
        unsigned b1 = f2bf(s1 * ww.y);
        ((unsigned*)weff)[idx] = b0 | (b1 << 16);
    }
}

// C[m,n] = sum_k A[m,k]*B[n,k]; A=[8192,1024], B=[1024,1024] bf16, C f32.
// 128x128 tile, BK=64, 4 waves (2x2), wave 4x4 of 16x16x32 MFMA.
// K-loop restructured as register-prefetch pipeline: global->VGPR loads for
// tile k+1 are issued before compute of tile k and only awaited (vmcnt(N))
// at the ds_write one phase later. Barriers carry no vmcnt drain (the m97
// global_load_lds structural stall). LDS layout/swizzle and all fragment /
// epilogue math identical to the verified R3 kernel (bit-identical output).
__global__ __launch_bounds__(256, 2) void gemm_bt(
        const unsigned short* __restrict__ A,
        const unsigned short* __restrict__ B,
        float* __restrict__ C) {
    constexpr int K = IN, BK = 64;
    constexpr int ES = 132;                        // epilogue row stride (floats)
    __shared__ __align__(16) char smem[32768];     // A 16K + B 16K; ebuf 32*132*4
    unsigned short* As = (unsigned short*)smem;    // 128 x 64 bf16
    unsigned short* Bs = As + 128 * BK;            // 128 x 64 bf16
    float* ebuf = (float*)smem;                    // epilogue reuse

    const int tid  = threadIdx.x;
    const int bm   = blockIdx.x, bn = blockIdx.y;
    const int lane = tid & 63;
    const int wave = tid >> 6;
    const int wm   = wave & 1, wn = wave >> 1;
    const int t    = lane & 15;    // M/N index within 16
    const int q    = lane >> 4;    // K-quad
    const int r8   = t & 7;        // XOR swizzle key

    // ---- staging: thread owns 4 16B chunks of A and of B per K-tile ----
    // global: linear chunk G = j*256+tid (coalesced); LDS: chunk c of row r
    // lands at slot (c ^ (r&7)) — same layout the verified reader expects.
    const unsigned short* gA[4]; const unsigned short* gB[4];
    unsigned short* lA[4]; unsigned short* lB[4];
#pragma unroll
    for (int j = 0; j < 4; ++j) {
        int G   = j * 256 + tid;
        int row = G >> 3;            // 8 chunks per 64-elem row
        int c   = G & 7;
        int sl  = row * 8 + (c ^ (row & 7));
        gA[j] = A + (size_t)(bm * 128 + row) * K + c * 8;
        gB[j] = B + (size_t)(bn * 128 + row) * K + c * 8;
        lA[j] = As + sl * 8;
        lB[j] = Bs + sl * 8;
    }

    // ---- fragment base pointers (verified): phys chunk (kh*4+q)^r8 ----
    const unsigned short* aB0 = As + (wm * 64 + t) * BK + ((0 + q) ^ r8) * 8;
    const unsigned short* aB1 = As + (wm * 64 + t) * BK + ((4 + q) ^ r8) * 8;
    const unsigned short* bB0 = Bs + (wn * 64 + t) * BK + ((0 + q) ^ r8) * 8;
    const unsigned short* bB1 = Bs + (wn * 64 + t) * BK + ((4 + q) ^ r8) * 8;

    floatx4 acc[4][4];
#pragma unroll
    for (int i = 0; i < 4; ++i)
#pragma unroll
        for (int j = 0; j < 4; ++j)
            acc[i][j] = (floatx4){0.f, 0.f, 0.f, 0.f};

    uint4 ra[4], rb[4], na[4], nb[4];

#define LOADT(RA, RB, KOFF)                                         \
    _Pragma("unroll")                                               \
    for (int j = 0; j < 4; ++j) {                                   \
        RA[j] = *(const uint4*)(gA[j] + (KOFF));                    \
        RB[j] = *(const uint4*)(gB[j] + (KOFF));                    \
    }

#define STORET(RA, RB)                                              \
    _Pragma("unroll")                                               \
    for (int j = 0; j < 4; ++j) {                                   \
        *(uint4*)lA[j] = RA[j];                                     \
        *(uint4*)lB[j] = RB[j];                                     \
    }

#define COMPUTE()                                                   \
    {                                                               \
        bf16x8 af[2][4], bfv[2][4];                                 \
        _Pragma("unroll")                                           \
        for (int i = 0; i < 4; ++i) {                               \
            af[0][i]  = *(const bf16x8*)(aB0 + i * 1024);           \
            af[1][i]  = *(const bf16x8*)(aB1 + i * 1024);           \
            bfv[0][i] = *(const bf16x8*)(bB0 + i * 1024);           \
            bfv[1][i] = *(const bf16x8*)(bB1 + i * 1024);           \
        }                                                           \
        _Pragma("unroll")                                           \
        for (int i = 0; i < 4; ++i)                                 \
            _Pragma("unroll")                                       \
            for (int j = 0; j < 4; ++j) {                           \
                acc[i][j] = __builtin_amdgcn_mfma_f32_16x16x32_bf16(\
                    af[0][i], bfv[0][j], acc[i][j], 0, 0, 0);       \
                acc[i][j] = __builtin_amdgcn_mfma_f32_16x16x32_bf16(\
                    af[1][i], bfv[1][j], acc[i][j], 0, 0, 0);       \
            }                                                       \
    }

    LOADT(ra, rb, 0);
    for (int k0 = 0; k0 < K; k0 += 2 * BK) {
        // ---- half 1: prefetch k0+BK, consume ra (tile k0) ----
        LOADT(na, nb, k0 + BK);          // in flight across the compute below
        STORET(ra, rb);                  // waits only ra/rb's loads (vmcnt(8))
        __syncthreads();                 // lgkm-only barrier
        COMPUTE();
        __syncthreads();
        // ---- half 2: prefetch k0+2BK (wrapped, harmless), consume na ----
        LOADT(ra, rb, (k0 + 2 * BK) & (K - 1));
        STORET(na, nb);
        __syncthreads();
        COMPUTE();
        __syncthreads();
    }
#undef LOADT
#undef STORET
#undef COMPUTE

    // ---- epilogue: 4 passes of 32 rows x 128 cols through ebuf ----
    // D layout: col = t, row = q*4 + reg  [m89/m91 verified]
#pragma unroll
    for (int p = 0; p < 4; ++p) {          // block rows [p*32, p*32+32)
        if (p) __syncthreads();
        if (wm == (p >> 1)) {
            int dt = p & 1;                // tm pair {2dt, 2dt+1}
#pragma unroll
            for (int half = 0; half < 2; ++half) {
                int tm = dt * 2 + half;
#pragma unroll
                for (int tn = 0; tn < 4; ++tn) {
                    int col = wn * 64 + tn * 16 + t;
#pragma unroll
                    for (int r = 0; r < 4; ++r) {
                        int brow = half * 16 + q * 4 + r;
                        ebuf[brow * ES + col] = acc[tm][tn][r];
                    }
                }
            }
        }
        __syncthreads();
#pragma unroll
        for (int rr = 0; rr < 4; ++rr) {
            int brow = rr * 8 + (tid >> 5);
            int col4 = tid & 31;
            float4 v = *(const float4*)(ebuf + brow * ES + col4 * 4);
            size_t grow = (size_t)(bm * 128 + p * 32 + brow);
            *(float4*)(C + grow * OUTD + bn * 128 + col4 * 4) = v;
        }
    }
}

extern "C" void kernel_launch(void* const* d_in, const int* in_sizes, int n_in,
                              void* d_out, int out_size, void* d_ws, size_t ws_size,
                              hipStream_t stream) {
    const float* x    = (const float*)d_in[0];
    const float* coef = (const float*)d_in[1];
    const float* w    = (const float*)d_in[2];
    float* out = (float*)d_out;

    unsigned short* xb   = (unsigned short*)d_ws;                                   // 16 MB
    unsigned short* weff = (unsigned short*)((char*)d_ws + (size_t)BATCH * IN * 2); // +2 MB

    prep_kernel<<<6144, 256, 0, stream>>>(x, coef, w, xb, weff);
    gemm_bt<<<dim3(BATCH / 128, OUTD / 128), 256, 0, stream>>>(xb, weff, out);
}

// Round 7
// 125.096 us; speedup vs baseline: 1.7091x; 1.7091x over previous
//
#include <hip/hip_runtime.h>
#include <hip/hip_bf16.h>
#include <stdint.h>

#define BATCH 8192
#define IN    1024
#define OUTD  1024
#define PBASIS 8

typedef __attribute__((ext_vector_type(8))) short bf16x8;
typedef __attribute__((ext_vector_type(4))) float floatx4;

__device__ __forceinline__ unsigned short f2bf(float f) {
    union { float f; unsigned u; } v; v.f = f;
    unsigned u = v.u;
    u += 0x7fffu + ((u >> 16) & 1u);   // RNE; inputs finite randn
    return (unsigned short)(u >> 16);
}

// Fused prep: blocks [0,4096) convert x -> bf16 (8 elem/thread);
// blocks [4096,6144) compute w_eff = bf16(sum_p coef * w) (2 elem/thread).
__global__ void prep_kernel(const float* __restrict__ x,
                            const float* __restrict__ coef,
                            const float* __restrict__ w,
                            unsigned short* __restrict__ xb,
                            unsigned short* __restrict__ weff) {
    int b = blockIdx.x;
    int tid = threadIdx.x;
    if (b < 4096) {
        int idx = b * 256 + tid;
        const float4* p = (const float4*)(x + (size_t)idx * 8);
        float4 a = p[0], c = p[1];
        uint4 o;
        o.x = (unsigned)f2bf(a.x) | ((unsigned)f2bf(a.y) << 16);
        o.y = (unsigned)f2bf(a.z) | ((unsigned)f2bf(a.w) << 16);
        o.z = (unsigned)f2bf(c.x) | ((unsigned)f2bf(c.y) << 16);
        o.w = (unsigned)f2bf(c.z) | ((unsigned)f2bf(c.w) << 16);
        ((uint4*)xb)[idx] = o;
    } else {
        int idx = (b - 4096) * 256 + tid;   // element pair index
        size_t e0 = (size_t)idx * 2;
        const float4* c4 = (const float4*)(coef + e0 * PBASIS);
        float4 a = c4[0], bb = c4[1], c = c4[2], d = c4[3];
        float s0 = (a.x + a.y + a.z + a.w) + (bb.x + bb.y + bb.z + bb.w);
        float s1 = (c.x + c.y + c.z + c.w) + (d.x + d.y + d.z + d.w);
        float2 ww = ((const float2*)w)[idx];
        unsigned b0 = f2bf(s0 * ww.x);
        unsigned b1 = f2bf(s1 * ww.y);
        ((unsigned*)weff)[idx] = b0 | (b1 << 16);
    }
}

// C[m,n] = sum_k A[m,k]*B[n,k]; A=[8192,1024], B=[1024,1024] bf16, C f32.
// 128x128 tile, BK=64, 4 waves (2x2), wave 4x4 of 16x16x32 MFMA.
// Register-prefetch pipeline, FULLY SCALARIZED (R6's array form was demoted
// to scratch: VGPR=68, 280 MB scratch writes). 16 named uint4 staging regs,
// 2x-unrolled ping-pong body, wave-uniform K offsets. Barriers carry only
// lgkmcnt; prefetch global loads stay in flight across the MFMA phase.
// LDS layout/swizzle/fragments/epilogue identical to verified R6 (passed).
__global__ __launch_bounds__(256, 2) void gemm_bt(
        const unsigned short* __restrict__ A,
        const unsigned short* __restrict__ B,
        float* __restrict__ C) {
    constexpr int K = IN, BK = 64;
    constexpr int ES = 132;                        // epilogue row stride (floats)
    __shared__ __align__(16) char smem[32768];     // A 16K + B 16K; ebuf 32*132*4
    unsigned short* As = (unsigned short*)smem;    // 128 x 64 bf16
    unsigned short* Bs = As + 128 * BK;            // 128 x 64 bf16
    float* ebuf = (float*)smem;                    // epilogue reuse

    const int tid  = threadIdx.x;
    const int bm   = blockIdx.x, bn = blockIdx.y;
    const int lane = tid & 63;
    const int wave = tid >> 6;
    const int wm   = wave & 1, wn = wave >> 1;
    const int t    = lane & 15;    // M/N index within 16
    const int q    = lane >> 4;    // K-quad
    const int r8   = t & 7;        // XOR swizzle key

    // ---- staging addresses (scalar, no arrays) ----
    // chunk G = j*256 + tid; row = G>>3; c = G&7; LDS slot = row*8 + (c^(row&7))
    int G0 = tid,       r0 = G0 >> 3, c0 = G0 & 7, s0i = r0 * 8 + (c0 ^ (r0 & 7));
    int G1 = 256 + tid, r1 = G1 >> 3, c1 = G1 & 7, s1i = r1 * 8 + (c1 ^ (r1 & 7));
    int G2 = 512 + tid, r2 = G2 >> 3, c2 = G2 & 7, s2i = r2 * 8 + (c2 ^ (r2 & 7));
    int G3 = 768 + tid, r3 = G3 >> 3, c3 = G3 & 7, s3i = r3 * 8 + (c3 ^ (r3 & 7));

    const unsigned short* gA0 = A + (size_t)(bm * 128 + r0) * K + c0 * 8;
    const unsigned short* gA1 = A + (size_t)(bm * 128 + r1) * K + c1 * 8;
    const unsigned short* gA2 = A + (size_t)(bm * 128 + r2) * K + c2 * 8;
    const unsigned short* gA3 = A + (size_t)(bm * 128 + r3) * K + c3 * 8;
    const unsigned short* gB0 = B + (size_t)(bn * 128 + r0) * K + c0 * 8;
    const unsigned short* gB1 = B + (size_t)(bn * 128 + r1) * K + c1 * 8;
    const unsigned short* gB2 = B + (size_t)(bn * 128 + r2) * K + c2 * 8;
    const unsigned short* gB3 = B + (size_t)(bn * 128 + r3) * K + c3 * 8;

    unsigned short* lA0 = As + s0i * 8;  unsigned short* lB0 = Bs + s0i * 8;
    unsigned short* lA1 = As + s1i * 8;  unsigned short* lB1 = Bs + s1i * 8;
    unsigned short* lA2 = As + s2i * 8;  unsigned short* lB2 = Bs + s2i * 8;
    unsigned short* lA3 = As + s3i * 8;  unsigned short* lB3 = Bs + s3i * 8;

    // ---- fragment base pointers (verified): phys chunk (kh*4+q)^r8 ----
    const unsigned short* aB0 = As + (wm * 64 + t) * BK + ((0 + q) ^ r8) * 8;
    const unsigned short* aB1 = As + (wm * 64 + t) * BK + ((4 + q) ^ r8) * 8;
    const unsigned short* bB0 = Bs + (wn * 64 + t) * BK + ((0 + q) ^ r8) * 8;
    const unsigned short* bB1 = Bs + (wn * 64 + t) * BK + ((4 + q) ^ r8) * 8;

    floatx4 acc[4][4];
#pragma unroll
    for (int i = 0; i < 4; ++i)
#pragma unroll
        for (int j = 0; j < 4; ++j)
            acc[i][j] = (floatx4){0.f, 0.f, 0.f, 0.f};

#define COMPUTE()                                                   \
    {                                                               \
        bf16x8 af0, af1, af2, af3, ag0, ag1, ag2, ag3;              \
        bf16x8 bf0, bf1, bf2, bf3, bg0, bg1, bg2, bg3;              \
        af0 = *(const bf16x8*)(aB0 + 0 * 1024);                     \
        af1 = *(const bf16x8*)(aB0 + 1 * 1024);                     \
        af2 = *(const bf16x8*)(aB0 + 2 * 1024);                     \
        af3 = *(const bf16x8*)(aB0 + 3 * 1024);                     \
        ag0 = *(const bf16x8*)(aB1 + 0 * 1024);                     \
        ag1 = *(const bf16x8*)(aB1 + 1 * 1024);                     \
        ag2 = *(const bf16x8*)(aB1 + 2 * 1024);                     \
        ag3 = *(const bf16x8*)(aB1 + 3 * 1024);                     \
        bf0 = *(const bf16x8*)(bB0 + 0 * 1024);                     \
        bf1 = *(const bf16x8*)(bB0 + 1 * 1024);                     \
        bf2 = *(const bf16x8*)(bB0 + 2 * 1024);                     \
        bf3 = *(const bf16x8*)(bB0 + 3 * 1024);                     \
        bg0 = *(const bf16x8*)(bB1 + 0 * 1024);                     \
        bg1 = *(const bf16x8*)(bB1 + 1 * 1024);                     \
        bg2 = *(const bf16x8*)(bB1 + 2 * 1024);                     \
        bg3 = *(const bf16x8*)(bB1 + 3 * 1024);                     \
        bf16x8 afv[4] = {af0, af1, af2, af3};                       \
        bf16x8 agv[4] = {ag0, ag1, ag2, ag3};                       \
        bf16x8 bfv[4] = {bf0, bf1, bf2, bf3};                       \
        bf16x8 bgv[4] = {bg0, bg1, bg2, bg3};                       \
        _Pragma("unroll")                                           \
        for (int i = 0; i < 4; ++i)                                 \
            _Pragma("unroll")                                       \
            for (int j = 0; j < 4; ++j) {                           \
                acc[i][j] = __builtin_amdgcn_mfma_f32_16x16x32_bf16(\
                    afv[i], bfv[j], acc[i][j], 0, 0, 0);            \
                acc[i][j] = __builtin_amdgcn_mfma_f32_16x16x32_bf16(\
                    agv[i], bgv[j], acc[i][j], 0, 0, 0);            \
            }                                                       \
    }

    uint4 ca0, ca1, ca2, ca3, cb0, cb1, cb2, cb3;   // current tile
    uint4 pa0, pa1, pa2, pa3, pb0, pb1, pb2, pb3;   // prefetch tile

    // prologue: tile 0
    ca0 = *(const uint4*)gA0; ca1 = *(const uint4*)gA1;
    ca2 = *(const uint4*)gA2; ca3 = *(const uint4*)gA3;
    cb0 = *(const uint4*)gB0; cb1 = *(const uint4*)gB1;
    cb2 = *(const uint4*)gB2; cb3 = *(const uint4*)gB3;

    for (int it = 0; it < K / (2 * BK); ++it) {
        const int k1 = ((2 * it + 1) * BK);            // <= 960, in-bounds
        const int k2 = ((2 * it + 2) * BK) & (K - 1);  // wraps to 0 at the end
        // ---- half 1: store cur, prefetch k1, compute ----
        *(uint4*)lA0 = ca0; *(uint4*)lA1 = ca1; *(uint4*)lA2 = ca2; *(uint4*)lA3 = ca3;
        *(uint4*)lB0 = cb0; *(uint4*)lB1 = cb1; *(uint4*)lB2 = cb2; *(uint4*)lB3 = cb3;
        __syncthreads();
        pa0 = *(const uint4*)(gA0 + k1); pa1 = *(const uint4*)(gA1 + k1);
        pa2 = *(const uint4*)(gA2 + k1); pa3 = *(const uint4*)(gA3 + k1);
        pb0 = *(const uint4*)(gB0 + k1); pb1 = *(const uint4*)(gB1 + k1);
        pb2 = *(const uint4*)(gB2 + k1); pb3 = *(const uint4*)(gB3 + k1);
        COMPUTE();
        __syncthreads();
        // ---- half 2: store prefetched, prefetch k2 into cur, compute ----
        *(uint4*)lA0 = pa0; *(uint4*)lA1 = pa1; *(uint4*)lA2 = pa2; *(uint4*)lA3 = pa3;
        *(uint4*)lB0 = pb0; *(uint4*)lB1 = pb1; *(uint4*)lB2 = pb2; *(uint4*)lB3 = pb3;
        __syncthreads();
        ca0 = *(const uint4*)(gA0 + k2); ca1 = *(const uint4*)(gA1 + k2);
        ca2 = *(const uint4*)(gA2 + k2); ca3 = *(const uint4*)(gA3 + k2);
        cb0 = *(const uint4*)(gB0 + k2); cb1 = *(const uint4*)(gB1 + k2);
        cb2 = *(const uint4*)(gB2 + k2); cb3 = *(const uint4*)(gB3 + k2);
        COMPUTE();
        __syncthreads();
    }
#undef COMPUTE

    // ---- epilogue: 4 passes of 32 rows x 128 cols through ebuf ----
    // D layout: col = t, row = q*4 + reg  [m89/m91 verified]
#pragma unroll
    for (int p = 0; p < 4; ++p) {          // block rows [p*32, p*32+32)
        if (p) __syncthreads();
        if (wm == (p >> 1)) {
            int dt = p & 1;                // tm pair {2dt, 2dt+1}
#pragma unroll
            for (int half = 0; half < 2; ++half) {
                int tm = dt * 2 + half;
#pragma unroll
                for (int tn = 0; tn < 4; ++tn) {
                    int col = wn * 64 + tn * 16 + t;
#pragma unroll
                    for (int r = 0; r < 4; ++r) {
                        int brow = half * 16 + q * 4 + r;
                        ebuf[brow * ES + col] = acc[tm][tn][r];
                    }
                }
            }
        }
        __syncthreads();
#pragma unroll
        for (int rr = 0; rr < 4; ++rr) {
            int brow = rr * 8 + (tid >> 5);
            int col4 = tid & 31;
            float4 v = *(const float4*)(ebuf + brow * ES + col4 * 4);
            size_t grow = (size_t)(bm * 128 + p * 32 + brow);
            *(float4*)(C + grow * OUTD + bn * 128 + col4 * 4) = v;
        }
    }
}

extern "C" void kernel_launch(void* const* d_in, const int* in_sizes, int n_in,
                              void* d_out, int out_size, void* d_ws, size_t ws_size,
                              hipStream_t stream) {
    const float* x    = (const float*)d_in[0];
    const float* coef = (const float*)d_in[1];
    const float* w    = (const float*)d_in[2];
    float* out = (float*)d_out;

    unsigned short* xb   = (unsigned short*)d_ws;                                   // 16 MB
    unsigned short* weff = (unsigned short*)((char*)d_ws + (size_t)BATCH * IN * 2); // +2 MB

    prep_kernel<<<6144, 256, 0, stream>>>(x, coef, w, xb, weff);
    gemm_bt<<<dim3(BATCH / 128, OUTD / 128), 256, 0, stream>>>(xb, weff, out);
}